// Round 5
// baseline (903.042 us; speedup 1.0000x reference)
//
#include <hip/hip_runtime.h>
#include <stdint.h>

#define DEV __device__ __forceinline__

// ---------------- constants ----------------
#define BB 8
#define TT 12
#define NN 4096
#define FF 64
#define HH 64
#define KK 8
#define LL 5
#define ALPHA 0.15f
#define TINYF 1.17549435e-38f

// ---------------- threefry2x32 (JAX-compatible, 20 rounds) ----------------
DEV uint32_t rotl32(uint32_t v, int r) { return (v << r) | (v >> (32 - r)); }

DEV void threefry(uint32_t k0, uint32_t k1, uint32_t x0, uint32_t x1,
                  uint32_t& o0, uint32_t& o1) {
  uint32_t ks2 = k0 ^ k1 ^ 0x1BD11BDAu;
  x0 += k0; x1 += k1;
#define RND(R) x0 += x1; x1 = rotl32(x1, R); x1 ^= x0;
  RND(13) RND(15) RND(26) RND(6)
  x0 += k1; x1 += ks2 + 1u;
  RND(17) RND(29) RND(16) RND(24)
  x0 += ks2; x1 += k0 + 2u;
  RND(13) RND(15) RND(26) RND(6)
  x0 += k0; x1 += k1 + 3u;
  RND(17) RND(29) RND(16) RND(24)
  x0 += k1; x1 += ks2 + 4u;
  RND(13) RND(15) RND(26) RND(6)
  x0 += ks2; x1 += k0 + 5u;
#undef RND
  o0 = x0; o1 = x1;
}

// ---- JAX threefry_partitionable=True (default since 0.4.36) semantics ----
// split(key, n): child i = threefry2x32(key, (0, i)); both words are the key.
DEV void split_child(uint32_t k0, uint32_t k1, uint32_t i,
                     uint32_t& c0, uint32_t& c1) {
  threefry(k0, k1, 0u, i, c0, c1);
}
// random_bits(key, 32, (S,)): word i = xor of the two threefry outputs at
// counter (hi64(i)=0, lo64(i)=i).
DEV uint32_t rbits(uint32_t k0, uint32_t k1, uint32_t i) {
  uint32_t a, b;
  threefry(k0, k1, 0u, i, a, b);
  return a ^ b;
}

// JAX uniform bit manipulation: bitcast((bits>>9)|0x3F800000) - 1.0 in [0,1)
DEV float bits_to_f(uint32_t w) {
  return __uint_as_float((w >> 9) | 0x3F800000u) - 1.0f;
}

// ---------------- kernel 1: fchange[b,n] = mean_{t,f} |nf[t+1]-nf[t]| ----------------
// grid = B * (N/16) = 2048 blocks, 256 threads; thread -> (node = tid>>4, chunk c = tid&15)
__global__ void k_fchange(const float* __restrict__ nf, float* __restrict__ fchange) {
  int blk = blockIdx.x;
  int b = blk >> 8;
  int n0 = (blk & 255) << 4;
  int tid = threadIdx.x;
  int node = n0 + (tid >> 4);
  int c = tid & 15;
  const float4* base = (const float4*)nf;
  float acc = 0.f;
  float4 prev;
  for (int t = 0; t < TT; ++t) {
    size_t o = ((size_t)(b * TT + t) * NN + node) * (FF / 4) + c;
    float4 v = base[o];
    if (t) {
      acc += fabsf(v.x - prev.x) + fabsf(v.y - prev.y) +
             fabsf(v.z - prev.z) + fabsf(v.w - prev.w);
    }
    prev = v;
  }
  acc += __shfl_xor(acc, 1);
  acc += __shfl_xor(acc, 2);
  acc += __shfl_xor(acc, 4);
  acc += __shfl_xor(acc, 8);
  if (c == 0) fchange[b * NN + node] = acc / 704.0f;  // (T-1)*F = 11*64
}

// ---------------- kernel 1b: acc_sum[b] (deterministic tree reduce) ----------------
__global__ void k_accsum(const float* __restrict__ fchange, float* __restrict__ acc_sum) {
  int b = blockIdx.x;
  int tid = threadIdx.x;
  __shared__ float red[256];
  float s = 0.f;
  for (int i = tid; i < NN; i += 256) s += fchange[b * NN + i];
  red[tid] = s; __syncthreads();
  for (int st = 128; st; st >>= 1) {
    if (tid < st) red[tid] += red[tid + st];
    __syncthreads();
  }
  if (!tid) acc_sum[b] = red[0];
}

// ---------------- kernel 2: scaled[b,n] = logits * fchange ----------------
__global__ void k_logits(const float* __restrict__ nf,
                         const float* __restrict__ W1, const float* __restrict__ b1,
                         const float* __restrict__ W2, const float* __restrict__ b2,
                         const float* __restrict__ fchange, float* __restrict__ scaled) {
  __shared__ float4 W1s[HH * 16];
  __shared__ float b1s[HH], W2s[HH];
  __shared__ float b2s;
  int tid = threadIdx.x;
  for (int i = tid; i < HH * 16; i += 256) W1s[i] = ((const float4*)W1)[i];
  if (tid < HH) { b1s[tid] = b1[tid]; W2s[tid] = W2[tid]; }
  if (!tid) b2s = b2[0];
  __syncthreads();
  int gid = blockIdx.x * 256 + tid;   // 0..32767
  int b = gid >> 12, n = gid & (NN - 1);
  const float4* xp = (const float4*)(nf + (((size_t)b * TT + (TT - 1)) * NN + n) * FF);
  float4 x[16];
#pragma unroll
  for (int i = 0; i < 16; ++i) x[i] = xp[i];
  float acc = 0.f;
  for (int j = 0; j < HH; ++j) {
    float d = 0.f;
#pragma unroll
    for (int i = 0; i < 16; ++i) {
      float4 w = W1s[j * 16 + i];
      d += x[i].x * w.x + x[i].y * w.y + x[i].z * w.z + x[i].w * w.w;
    }
    float h = fmaxf(d + b1s[j], 0.f);
    acc += h * W2s[j];
  }
  scaled[gid] = (acc + b2s) * fchange[gid];
}

// ---------------- kernel 3: top-8 per batch (ties -> lower index) ----------------
__global__ void k_top8(const float* __restrict__ scaled, int* __restrict__ src) {
  int b = blockIdx.x;
  int tid = threadIdx.x;   // 256
  __shared__ float vals[NN];
  __shared__ float rf[256];
  __shared__ int ri[256];
  for (int i = tid; i < NN; i += 256) vals[i] = scaled[b * NN + i];
  __syncthreads();
  for (int k = 0; k < KK; ++k) {
    float bv = -INFINITY; int bi = 0x7FFFFFFF;
    for (int i = tid; i < NN; i += 256) {
      float v = vals[i];
      if (v > bv || (v == bv && i < bi)) { bv = v; bi = i; }
    }
    rf[tid] = bv; ri[tid] = bi; __syncthreads();
    for (int st = 128; st; st >>= 1) {
      if (tid < st) {
        float v = rf[tid + st]; int ix = ri[tid + st];
        if (v > rf[tid] || (v == rf[tid] && ix < ri[tid])) { rf[tid] = v; ri[tid] = ix; }
      }
      __syncthreads();
    }
    if (!tid) { src[b * KK + k] = ri[0]; vals[ri[0]] = -INFINITY; }
    __syncthreads();
  }
}

// ---------------- kernel 4: random walks (one block per (b,k)) ----------------
#define WT 512
__global__ void k_walk(const float* __restrict__ nf, const float* __restrict__ adj,
                       const float* __restrict__ fchange, const float* __restrict__ acc_sum,
                       const int* __restrict__ src, int* __restrict__ path_ws,
                       float* __restrict__ out_paths) {
  int blk = blockIdx.x;   // b*K + k
  int b = blk >> 3;
  int tid = threadIdx.x;
  __shared__ float diff[NN];
  __shared__ unsigned char vis[NN];
  __shared__ float fc[FF];
  __shared__ float rf[WT];
  __shared__ int ri[WT];
  __shared__ float rm[WT];
  __shared__ int s_path[LL];
  __shared__ int s_cur, s_done;

  const float* feats = nf + (((size_t)b * TT + (TT - 1)) * NN) * FF;  // nf_last[b]
  const float* fch = fchange + b * NN;
  float dden = acc_sum[b] + 1e-8f;
  int source = src[blk];

  for (int i = tid; i < NN; i += WT) vis[i] = 0;
  __syncthreads();
  if (!tid) {
    for (int t = 0; t < LL; ++t) s_path[t] = source;
    s_cur = source; s_done = 0; vis[source] = 1;
  }
  __syncthreads();

  // wkeys: partitionable split of key(42)=(0,42) into 64 children; flat index blk
  uint32_t wk0, wk1;
  split_child(0u, 42u, (uint32_t)blk, wk0, wk1);

  for (int i = 0; i < LL - 1; ++i) {
    int done = s_done;
    int cur = s_cur;
    if (done) continue;   // block-uniform

    uint32_t ki0, ki1, ku0, ku1, kc0, kc1;
    split_child(wk0, wk1, (uint32_t)i, ki0, ki1);   // keys[i] of split(wkey, 4)
    split_child(ki0, ki1, 0u, ku0, ku1);            // ku
    split_child(ki0, ki1, 1u, kc0, kc1);            // kc

    float uf = bits_to_f(rbits(ku0, ku1, 0u));      // scalar uniform [0,1)
    bool tele = uf < ALPHA;

    if (tele) {
      if (!tid) { s_path[i + 1] = source; s_cur = source; vis[source] = 1; }
      __syncthreads();
      continue;
    }

    for (int f = tid; f < FF; f += WT) fc[f] = feats[(size_t)cur * FF + f];
    __syncthreads();

    // pass A: diff[n] = ||feats[n] - feats[cur]||, reduce max
    float lmax = -INFINITY;
    for (int n = tid; n < NN; n += WT) {
      const float4* xp = (const float4*)(feats + (size_t)n * FF);
      float s = 0.f;
#pragma unroll
      for (int q = 0; q < 16; ++q) {
        float4 v = xp[q];
        float t0 = v.x - fc[q * 4 + 0]; s += t0 * t0;
        float t1 = v.y - fc[q * 4 + 1]; s += t1 * t1;
        float t2 = v.z - fc[q * 4 + 2]; s += t2 * t2;
        float t3 = v.w - fc[q * 4 + 3]; s += t3 * t3;
      }
      float dn = sqrtf(s);
      diff[n] = dn;
      lmax = fmaxf(lmax, dn);
    }
    rf[tid] = lmax; __syncthreads();
    for (int st = WT / 2; st; st >>= 1) {
      if (tid < st) rf[tid] = fmaxf(rf[tid], rf[tid + st]);
      __syncthreads();
    }
    float m = rf[0];
    __syncthreads();
    float mden = fmaxf(m, 1e-38f);

    // pass B: probs, gumbel scores, argmax + masked sum
    const float* arow = adj + ((size_t)b * NN + cur) * NN;
    float best = -INFINITY; int bidx = 0x7FFFFFFF; float msum = 0.f;
    for (int n = tid; n < NN; n += WT) {
      uint32_t w = rbits(kc0, kc1, (uint32_t)n);     // partitionable bits word n
      float f = bits_to_f(w);
      float u = fmaxf(TINYF, f + TINYF);             // uniform(minval=tiny, maxval=1)
      float g = -logf(-logf(u));                     // gumbel
      float a = vis[n] ? 0.f : arow[n];
      msum += a;
      float gd = (m > 0.f) ? (diff[n] / mden) : 0.f;
      float prob = a * (1.f + fch[n] / dden) * (1.f + gd);
      float sc = (prob > 0.f) ? (g + logf(fmaxf(prob, 1e-38f))) : -INFINITY;
      if (sc > best || (sc == best && n < bidx)) { best = sc; bidx = n; }
    }
    rf[tid] = best; ri[tid] = bidx; rm[tid] = msum; __syncthreads();
    for (int st = WT / 2; st; st >>= 1) {
      if (tid < st) {
        float v = rf[tid + st]; int ix = ri[tid + st];
        if (v > rf[tid] || (v == rf[tid] && ix < ri[tid])) { rf[tid] = v; ri[tid] = ix; }
        rm[tid] += rm[tid + st];
      }
      __syncthreads();
    }
    int sampled = ri[0];
    bool dead = (rm[0] <= 0.f);
    if (!tid) {
      if (!dead) { s_path[i + 1] = sampled; s_cur = sampled; vis[sampled] = 1; }
      else s_done = 1;
    }
    __syncthreads();
  }

  if (tid < LL) {
    path_ws[blk * LL + tid] = s_path[tid];
    out_paths[blk * LL + tid] = (float)s_path[tid];
  }
}

// ---------------- kernel 5: biGRU (5 fwd steps + 1 bwd step) + pf + score ----------------
__global__ void k_gru(const float* __restrict__ nf, const int* __restrict__ path_ws,
                      const float* __restrict__ Wih_f, const float* __restrict__ Whh_f,
                      const float* __restrict__ bih_f, const float* __restrict__ bhh_f,
                      const float* __restrict__ Wih_b, const float* __restrict__ Whh_b,
                      const float* __restrict__ bih_b, const float* __restrict__ bhh_b,
                      const float* __restrict__ W_ps1, const float* __restrict__ b_ps1,
                      const float* __restrict__ W_ps2, const float* __restrict__ b_ps2,
                      float* __restrict__ out_pf, float* __restrict__ scores) {
  int blk = blockIdx.x;   // b*K + k
  int b = blk >> 3;
  int j = threadIdx.x;    // 64
  __shared__ float x[FF], h[HH], pf[2 * HH], red[HH];
  const float* feats = nf + (((size_t)b * TT + (TT - 1)) * NN) * FF;
  int pth[LL];
#pragma unroll
  for (int t = 0; t < LL; ++t) pth[t] = path_ws[blk * LL + t];

  float hj = 0.f;
  h[j] = 0.f;
  __syncthreads();

  // forward GRU, 5 steps
  for (int t = 0; t < LL; ++t) {
    x[j] = feats[(size_t)pth[t] * FF + j];
    __syncthreads();
    float gir = bih_f[j], giz = bih_f[HH + j], gin = bih_f[2 * HH + j];
    float ghr = bhh_f[j], ghz = bhh_f[HH + j], ghn = bhh_f[2 * HH + j];
    const float4* xr = (const float4*)x;
    const float4* hr = (const float4*)h;
    const float4* wr = (const float4*)(Wih_f + (size_t)j * FF);
    const float4* wz = (const float4*)(Wih_f + (size_t)(HH + j) * FF);
    const float4* wn = (const float4*)(Wih_f + (size_t)(2 * HH + j) * FF);
    const float4* vr = (const float4*)(Whh_f + (size_t)j * HH);
    const float4* vz = (const float4*)(Whh_f + (size_t)(HH + j) * HH);
    const float4* vn = (const float4*)(Whh_f + (size_t)(2 * HH + j) * HH);
#pragma unroll 4
    for (int q = 0; q < 16; ++q) {
      float4 xv = xr[q], hv = hr[q], w;
      w = wr[q]; gir += w.x * xv.x + w.y * xv.y + w.z * xv.z + w.w * xv.w;
      w = wz[q]; giz += w.x * xv.x + w.y * xv.y + w.z * xv.z + w.w * xv.w;
      w = wn[q]; gin += w.x * xv.x + w.y * xv.y + w.z * xv.z + w.w * xv.w;
      w = vr[q]; ghr += w.x * hv.x + w.y * hv.y + w.z * hv.z + w.w * hv.w;
      w = vz[q]; ghz += w.x * hv.x + w.y * hv.y + w.z * hv.z + w.w * hv.w;
      w = vn[q]; ghn += w.x * hv.x + w.y * hv.y + w.z * hv.z + w.w * hv.w;
    }
    float r = 1.f / (1.f + expf(-(gir + ghr)));
    float z = 1.f / (1.f + expf(-(giz + ghz)));
    float nn2 = tanhf(gin + r * ghn);
    hj = (1.f - z) * nn2 + z * hj;
    __syncthreads();
    h[j] = hj;
    __syncthreads();
  }
  pf[j] = hj;   // fwd[:, -1]

  // backward GRU: only step 0 of reversed scan = one cell step on x[:, L-1], h0=0
  x[j] = feats[(size_t)pth[LL - 1] * FF + j];
  __syncthreads();
  {
    float gir = bih_b[j], giz = bih_b[HH + j], gin = bih_b[2 * HH + j];
    const float4* xr = (const float4*)x;
    const float4* wr = (const float4*)(Wih_b + (size_t)j * FF);
    const float4* wz = (const float4*)(Wih_b + (size_t)(HH + j) * FF);
    const float4* wn = (const float4*)(Wih_b + (size_t)(2 * HH + j) * FF);
#pragma unroll 4
    for (int q = 0; q < 16; ++q) {
      float4 xv = xr[q], w;
      w = wr[q]; gir += w.x * xv.x + w.y * xv.y + w.z * xv.z + w.w * xv.w;
      w = wz[q]; giz += w.x * xv.x + w.y * xv.y + w.z * xv.z + w.w * xv.w;
      w = wn[q]; gin += w.x * xv.x + w.y * xv.y + w.z * xv.z + w.w * xv.w;
    }
    float r = 1.f / (1.f + expf(-(gir + bhh_b[j])));
    float z = 1.f / (1.f + expf(-(giz + bhh_b[HH + j])));
    float nn2 = tanhf(gin + r * bhh_b[2 * HH + j]);
    pf[HH + j] = (1.f - z) * nn2;   // + z*0
  }
  __syncthreads();

  out_pf[(size_t)blk * 2 * HH + j] = pf[j];
  out_pf[(size_t)blk * 2 * HH + HH + j] = pf[HH + j];

  // score = sigmoid(relu(pf @ W_ps1.T + b_ps1) @ W_ps2.T + b_ps2)
  float s1 = b_ps1[j];
  const float4* pp = (const float4*)pf;
  const float4* wp = (const float4*)(W_ps1 + (size_t)j * 2 * HH);
#pragma unroll 8
  for (int q = 0; q < 32; ++q) {
    float4 w = wp[q], v = pp[q];
    s1 += w.x * v.x + w.y * v.y + w.z * v.z + w.w * v.w;
  }
  s1 = fmaxf(s1, 0.f);
  red[j] = s1 * W_ps2[j];
  __syncthreads();
  for (int st = 32; st; st >>= 1) {
    if (j < st) red[j] += red[j + st];
    __syncthreads();
  }
  if (!j) scores[blk] = 1.f / (1.f + expf(-(red[0] + b_ps2[0])));
}

// ---------------- kernel 6: weights = softmax over K within each b ----------------
__global__ void k_weights(const float* __restrict__ scores, float* __restrict__ out_w) {
  int tid = threadIdx.x;  // 64 = B*K
  __shared__ float sv[BB * KK];
  sv[tid] = scores[tid];
  __syncthreads();
  int b = tid >> 3;
  float m = -INFINITY;
  for (int kk = 0; kk < KK; ++kk) m = fmaxf(m, sv[b * KK + kk]);
  float e = expf(sv[tid] - m);
  float s = 0.f;
  for (int kk = 0; kk < KK; ++kk) s += expf(sv[b * KK + kk] - m);
  out_w[tid] = e / s;
}

// ---------------- launcher ----------------
extern "C" void kernel_launch(void* const* d_in, const int* in_sizes, int n_in,
                              void* d_out, int out_size, void* d_ws, size_t ws_size,
                              hipStream_t stream) {
  const float* nf    = (const float*)d_in[0];
  const float* adj   = (const float*)d_in[1];
  const float* W_sp1 = (const float*)d_in[2];
  const float* b_sp1 = (const float*)d_in[3];
  const float* W_sp2 = (const float*)d_in[4];
  const float* b_sp2 = (const float*)d_in[5];
  const float* Wih_f = (const float*)d_in[6];
  const float* Whh_f = (const float*)d_in[7];
  const float* bih_f = (const float*)d_in[8];
  const float* bhh_f = (const float*)d_in[9];
  const float* Wih_b = (const float*)d_in[10];
  const float* Whh_b = (const float*)d_in[11];
  const float* bih_b = (const float*)d_in[12];
  const float* bhh_b = (const float*)d_in[13];
  const float* W_ps1 = (const float*)d_in[14];
  const float* b_ps1 = (const float*)d_in[15];
  const float* W_ps2 = (const float*)d_in[16];
  const float* b_ps2 = (const float*)d_in[17];

  float* out       = (float*)d_out;
  float* out_paths = out;                 // B*K*L = 320 (paths as float)
  float* out_w     = out + 320;           // B*K*1 = 64
  float* out_pf    = out + 384;           // B*K*2H = 8192

  float* wsf     = (float*)d_ws;
  float* fchange = wsf;                   // 32768
  float* scaled  = wsf + 32768;           // 32768
  float* acc_sum = wsf + 65536;           // 8
  int*   srcw    = (int*)(wsf + 65552);   // 64 ints
  int*   path_ws = (int*)(wsf + 65552 + 64); // 320 ints
  float* scoresw = wsf + 66000;           // 64

  k_fchange<<<BB * (NN / 16), 256, 0, stream>>>(nf, fchange);
  k_accsum<<<BB, 256, 0, stream>>>(fchange, acc_sum);
  k_logits<<<(BB * NN) / 256, 256, 0, stream>>>(nf, W_sp1, b_sp1, W_sp2, b_sp2, fchange, scaled);
  k_top8<<<BB, 256, 0, stream>>>(scaled, srcw);
  k_walk<<<BB * KK, WT, 0, stream>>>(nf, adj, fchange, acc_sum, srcw, path_ws, out_paths);
  k_gru<<<BB * KK, HH, 0, stream>>>(nf, path_ws, Wih_f, Whh_f, bih_f, bhh_f,
                                    Wih_b, Whh_b, bih_b, bhh_b,
                                    W_ps1, b_ps1, W_ps2, b_ps2, out_pf, scoresw);
  k_weights<<<1, BB * KK, 0, stream>>>(scoresw, out_w);
}